// Round 3
// baseline (181.477 us; speedup 1.0000x reference)
//
#include <hip/hip_runtime.h>
#include <math.h>

#define Bq 4
#define Hh 16
#define Lq 1024
#define Dd 64
#define Kk 8
#define QT 128        // q rows per block (32 per wave PAIR, 4 pairs)
#define KT 128        // k rows per iteration; wave pair splits the 2 sub-tiles
#define TB 1152       // bias table entries per copy (2 shifted copies)
#define FMAX 8.0f     // fixed softmax shift (verified safe R1-R11)
#define LOG2E 1.44269504f

typedef __attribute__((ext_vector_type(8))) short short8;         // 8 bf16
typedef __attribute__((ext_vector_type(4))) unsigned int u32x4;   // 4 dwords
typedef __attribute__((ext_vector_type(16))) float f32x16;

// packed f32x2 -> bf16x2, round-half-up — BIT-IDENTICAL to R5's f2bh
// ((u+0x8000)>>16) but 3 VALU ops/pair via v_perm_b32 byte select.
// R9 post-mortem: __float22bfloat162_rn + reinterpret_cast took a local's
// address -> un-promoted alloca -> ~110 MB scratch traffic. Pure int ops only.
__device__ __forceinline__ unsigned int pk2(float a, float b) {
    return __builtin_amdgcn_perm(__float_as_uint(b) + 0x8000u,
                                 __float_as_uint(a) + 0x8000u,
                                 0x07060302u);
}

// j-permutation (verified R4-R11): V row j -> column slot so the S^T C/D
// register layout IS the PV A-fragment layout (P never touches LDS).
// jperm(j0+u) == jperm(j0)+u for j0%4==0, u<4 (low 2 bits map identity).
__device__ __forceinline__ int jperm(int j) {
    return (j & 32) | ((j & 8) << 1) | ((j & 4) << 1) | ((j & 16) >> 2) | (j & 3);
}

// ---------------------------------------------------------------------------
// R12 pre-pass: K/V f32 -> bf16 in workspace, ONCE per launch.
//   Kb[bh][j][d]   = bf16(K)            (pure elementwise cast)
//   Vt[bh][d][s]   = bf16(V^T), s = (j & ~63) | jperm(j & 63)
// Conversion uses the same pk2 as the old LDS staging -> bit-identical data.
// 1024 blocks x 256 threads = 262144 threads; Kb 2 grid-stride passes,
// Vt exactly one task per thread (64 bh x 16 d-quads x 256 j-quads).
// ---------------------------------------------------------------------------
__global__ __launch_bounds__(256) void conv_kernel(
    const float* __restrict__ kp, const float* __restrict__ vp,
    unsigned short* __restrict__ kb, unsigned short* __restrict__ vt)
{
    const int tid = blockIdx.x * 256 + threadIdx.x;
    #pragma unroll
    for (int it = 0; it < 2; ++it) {
        const int n = (it * 262144 + tid) * 8;      // < 4,194,304
        float4 x0 = *(const float4*)(kp + n);
        float4 x1 = *(const float4*)(kp + n + 4);
        u32x4 a;
        a[0] = pk2(x0.x, x0.y); a[1] = pk2(x0.z, x0.w);
        a[2] = pk2(x1.x, x1.y); a[3] = pk2(x1.z, x1.w);
        *(u32x4*)(kb + n) = a;
    }
    // V^T 4x4 micro-transpose, identical pairing to old LDS staging
    const int bh = tid >> 12;
    const int dt = (tid >> 8) & 15;
    const int jt = tid & 255;            // adjacent tids -> adjacent j: writes
    const int j0 = 4 * jt;               // land contiguous per 128B chunk
    const float* vsrc = vp + ((size_t)bh * Lq + j0) * Dd + 4 * dt;
    float4 r0 = *(const float4*)(vsrc);
    float4 r1 = *(const float4*)(vsrc + Dd);
    float4 r2 = *(const float4*)(vsrc + 2 * Dd);
    float4 r3 = *(const float4*)(vsrc + 3 * Dd);
    const int slot = (j0 & ~63) | jperm(j0 & 63);
    unsigned short* vd = vt + ((size_t)bh * Dd + 4 * dt) * Lq + slot;
    uint2 w;
    w.x = pk2(r0.x, r1.x); w.y = pk2(r2.x, r3.x); *(uint2*)(vd)          = w;
    w.x = pk2(r0.y, r1.y); w.y = pk2(r2.y, r3.y); *(uint2*)(vd + Lq)     = w;
    w.x = pk2(r0.z, r1.z); w.y = pk2(r2.z, r3.z); *(uint2*)(vd + 2 * Lq) = w;
    w.x = pk2(r0.w, r1.w); w.y = pk2(r2.w, r3.w); *(uint2*)(vd + 3 * Lq) = w;
}

// ---------------------------------------------------------------------------
// R12 main: BARRIER-FREE main loop — MFMA frags read directly from the
// bf16 workspace (L1/L2-resident: 2 MB/XCD working set; all 4 qw-waves of a
// block read identical addresses -> L1 hits).  Kills: K/V LDS staging
// (48 VALU + 12 ds_write/iter), K/V ds_read bank conflicts (3.67M cyc),
// and the per-iteration barrier that phase-locked all 8 waves (R10 showed
// wave desync is the lever: +27%; R11 showed barrier-count is not: 0%).
// LDS now only: bias table (2 copies, 9216 B) overlapped with the epilogue
// reduction scratch (34816 B total) — barrier after loop guards the overlap.
// Block = 512 (8 waves), grid (64, 8).  Wave w = (qw=w>>1, sw=w&1).
// mfma_f32_32x32x16_bf16.  S^T = K Q^T, C/D: col=lane&31 (=i q-row),
// row=(r&3)+8*(r>>2)+4*(lane>>5) (=j_loc).  O = P V via jperm trick.
// Bias fed as MFMA C-init (R11, verified).  Fixed-max softmax:
// p = exp2(S + (bias-FMAX)*log2e), Q pre-scaled 0.125*log2e.
// __launch_bounds__(512,2): 128-VGPR cap, spill-free (R6/R7: arg=4 capped
// VGPRs at 64 -> ~700 MB scratch spills. Never again.)
// ---------------------------------------------------------------------------
__global__ __launch_bounds__(512, 2) void attn_kernel(
    const float* __restrict__ qp,
    const float* __restrict__ off, const float* __restrict__ amp,
    const float* __restrict__ sh, const float* __restrict__ bpar,
    const unsigned short* __restrict__ kb,
    const unsigned short* __restrict__ vt,
    float* __restrict__ out)
{
    // 34816 B: [0,2304) floats = bias2 during loop; whole thing = epilogue
    // reduction scratch after the post-loop barrier (bias dead by then).
    __shared__ __align__(16) float smem_f[8 * 64 * 17];
    float* bias2 = smem_f;

    const int bh = blockIdx.x;            // fastest -> XCD = bh%8
    const int qs = blockIdx.y * QT;
    const int t  = threadIdx.x;
    const int w  = t >> 6;                // 0..7
    const int qw = w >> 1;                // q sub-block 0..3
    const int sw = w & 1;                 // k sub-tile 0/1
    const int lane = t & 63;
    const int l31 = lane & 31;
    const int h5  = lane >> 5;
    const int h   = bh & 15;

    // ---- bias copy 0: (log(ksum+eps+bp) - |rel|*slope - FMAX)*log2e ----
    float slope = (h < Hh - 2) ? 4.605170185988092f * exp2f(-6.0f * (float)h / 13.0f) : 0.0f;
    #pragma unroll
    for (int it = 0; it < 3; ++it) {
        int i = it * 512 + t;
        if (i < TB - 1) {
            float rel = (float)(i - 127 - qs);
            float ksum = 0.0f;
            #pragma unroll
            for (int kk = 0; kk < Kk; ++kk) {
                float a = amp[kk * Hh + h];
                float o = off[kk * Hh + h];
                float s = sh[kk * Hh + h];
                float sgn = (a > 0.0f) ? 1.0f : ((a < 0.0f) ? -1.0f : 0.0f);
                ksum += fabsf(a) / (1.0f + __expf(-sgn * (rel - o) / s));
            }
            bias2[i] = (logf(ksum + 1e-8f + bpar[h]) - fabsf(rel) * slope - FMAX) * LOG2E;
        }
    }

    // ---- Q B-frags (global, once), scale folded, packed converts ----
    const float QS = 0.125f * LOG2E;
    short8 bq[4];
    const float* qrow = qp + ((size_t)bh * Lq + qs + 32 * qw + l31) * Dd;
    #pragma unroll
    for (int c = 0; c < 4; ++c) {
        float4 x0 = *(const float4*)(qrow + c * 16 + h5 * 8);
        float4 x1 = *(const float4*)(qrow + c * 16 + h5 * 8 + 4);
        u32x4 a;
        a[0] = pk2(x0.x * QS, x0.y * QS);
        a[1] = pk2(x0.z * QS, x0.w * QS);
        a[2] = pk2(x1.x * QS, x1.y * QS);
        a[3] = pk2(x1.z * QS, x1.w * QS);
        bq[c] = __builtin_bit_cast(short8, a);
    }

    __syncthreads();                      // bias copy0 visible

    // ---- replicate bias copy 1 (copy1[i] = bias(i+1)) ----
    #pragma unroll
    for (int it = 0; it < 3; ++it) {
        int i = it * 512 + t;
        if (i < TB)
            bias2[TB + i] = bias2[i + 1 <= TB - 2 ? i + 1 : TB - 2];
    }
    __syncthreads();                      // bias complete; NO barriers below

    // ---- accumulators (partial over this wave's k sub-tiles) ----
    f32x16 O0, O1;
    #pragma unroll
    for (int r = 0; r < 16; ++r) { O0[r] = 0.f; O1[r] = 0.f; }
    float l_part = 0.0f;

    const int L0 = 4 * h5 - 32 * qw - l31 + 127;  // bias lane offset
    const int phi = L0 & 1;
    const float* bcopy = bias2 + phi * TB - phi;  // even-aligned float2 view

    // lane-folded frag base pointers (16B-aligned dwordx4 loads)
    const unsigned short* kbb = kb + ((size_t)bh * Lq + 64 * sw + l31) * Dd + h5 * 8;
    const unsigned short* vtb = vt + (size_t)bh * Dd * Lq + 64 * sw + h5 * 8;

    #pragma unroll 1
    for (int kt = 0; kt < Lq / KT; ++kt) {        // 8 iterations, no barriers
        const int ks = kt * KT;

        // ---- issue all 16 frag loads up front (K first: QK waits only on
        // them, V's 8 stay in flight through softmax) ----
        short8 ka0[4], ka1[4], vf0[4], vf1[4];    // const-indexed (unrolled)
        #pragma unroll
        for (int c = 0; c < 4; ++c) {
            ka0[c] = *(const short8*)(kbb + (size_t)ks * Dd + c * 16);
            ka1[c] = *(const short8*)(kbb + (size_t)ks * Dd + 32 * Dd + c * 16);
        }
        #pragma unroll
        for (int c = 0; c < 4; ++c) {
            vf0[c] = *(const short8*)(vtb + (size_t)l31 * Lq + ks + c * 16);
            vf1[c] = *(const short8*)(vtb + (size_t)(32 + l31) * Lq + ks + c * 16);
        }

        // ---- S init = bias (MFMA C-in), hides K-load latency ----
        f32x16 S0, S1;
        #pragma unroll
        for (int p = 0; p < 4; ++p) {
            int base0 = ks + 64 * sw + 8 * p + L0;
            float2 a0 = *(const float2*)(bcopy + base0);
            float2 a1 = *(const float2*)(bcopy + base0 + 2);
            float2 a2 = *(const float2*)(bcopy + base0 + 32);
            float2 a3 = *(const float2*)(bcopy + base0 + 34);
            S0[4 * p + 0] = a0.x; S0[4 * p + 1] = a0.y;
            S0[4 * p + 2] = a1.x; S0[4 * p + 3] = a1.y;
            S1[4 * p + 0] = a2.x; S1[4 * p + 1] = a2.y;
            S1[4 * p + 2] = a3.x; S1[4 * p + 3] = a3.y;
        }

        // ---- S^T = K Q^T + bias (this wave's sub-tile sw) ----
        #pragma unroll
        for (int c = 0; c < 4; ++c)
            S0 = __builtin_amdgcn_mfma_f32_32x32x16_bf16(ka0[c], bq[c], S0, 0, 0, 0);
        #pragma unroll
        for (int c = 0; c < 4; ++c)
            S1 = __builtin_amdgcn_mfma_f32_32x32x16_bf16(ka1[c], bq[c], S1, 0, 0, 0);

        // ---- softmax: p = exp2(S) (bias already inside) ----
        float lsum = 0.0f;
        #pragma unroll
        for (int r = 0; r < 16; ++r) {
            float e0 = __builtin_amdgcn_exp2f(S0[r]);
            float e1 = __builtin_amdgcn_exp2f(S1[r]);
            S0[r] = e0; S1[r] = e1;
            lsum += e0 + e1;
        }
        l_part += lsum;

        // ---- P A-frags in-register (jperm trick), packed converts ----
        short8 ap[4];
        #pragma unroll
        for (int c = 0; c < 4; ++c) {
            int b = (c & 1) * 4;
            u32x4 a;
            if (c >> 1) {
                a[0] = pk2(S1[b + 0], S1[b + 1]);
                a[1] = pk2(S1[b + 2], S1[b + 3]);
                a[2] = pk2(S1[b + 8], S1[b + 9]);
                a[3] = pk2(S1[b + 10], S1[b + 11]);
            } else {
                a[0] = pk2(S0[b + 0], S0[b + 1]);
                a[1] = pk2(S0[b + 2], S0[b + 3]);
                a[2] = pk2(S0[b + 8], S0[b + 9]);
                a[3] = pk2(S0[b + 10], S0[b + 11]);
            }
            ap[c] = __builtin_bit_cast(short8, a);
        }

        // ---- O += P V (sub-tile sw) ----
        #pragma unroll
        for (int c = 0; c < 4; ++c)
            O0 = __builtin_amdgcn_mfma_f32_32x32x16_bf16(ap[c], vf0[c], O0, 0, 0, 0);
        #pragma unroll
        for (int c = 0; c < 4; ++c)
            O1 = __builtin_amdgcn_mfma_f32_32x32x16_bf16(ap[c], vf1[c], O1, 0, 0, 0);
    }

    // ---- epilogue: wave pair (qw,0)+(qw,1) combine, normalize, store ----
    // Barrier first: bias2 must be dead in ALL waves before scratch reuse.
    __syncthreads();
    l_part += __shfl_xor(l_part, 32);     // combine j-halves within wave
    float* red = smem_f;
    const int rb = (w * 64 + lane) * 17;  // stride 17 dwords: 2-way alias only
    #pragma unroll
    for (int r = 0; r < 16; ++r) red[rb + r] = sw ? O0[r] : O1[r];
    red[rb + 16] = l_part;
    __syncthreads();
    const int pb = ((w ^ 1) * 64 + lane) * 17;
    float inv = 1.0f / (l_part + red[pb + 16]);
    float* ob = out + ((size_t)bh * Lq + qs + 32 * qw) * Dd;
    #pragma unroll
    for (int r = 0; r < 16; ++r) {
        float o = (sw ? O1[r] : O0[r]) + red[pb + r];
        int rowp = (r & 3) + 8 * (r >> 2) + 4 * h5;
        float invp = __shfl(inv, rowp, 32);   // l lives at lane l31==row
        ob[(size_t)rowp * Dd + 32 * sw + l31] = o * invp;  // sw picks col half
    }
}

extern "C" void kernel_launch(void* const* d_in, const int* in_sizes, int n_in,
                              void* d_out, int out_size, void* d_ws, size_t ws_size,
                              hipStream_t stream) {
    const float* q   = (const float*)d_in[0];
    const float* k   = (const float*)d_in[1];
    const float* v   = (const float*)d_in[2];
    const float* off = (const float*)d_in[3];
    const float* amp = (const float*)d_in[4];
    const float* sh  = (const float*)d_in[5];
    const float* bp  = (const float*)d_in[6];
    float* out = (float*)d_out;

    // workspace: Kb (8 MiB) | Vt (8 MiB) — 16,777,216 B total
    unsigned short* kb = (unsigned short*)d_ws;
    unsigned short* vt = kb + (size_t)Bq * Hh * Lq * Dd;

    conv_kernel<<<dim3(1024), 256, 0, stream>>>(k, v, kb, vt);

    dim3 grid(Bq * Hh, Lq / QT);          // (64, 8), bh fastest -> XCD locality
    attn_kernel<<<grid, 512, 0, stream>>>(q, off, amp, sh, bp, kb, vt, out);
}

// Round 4
// 152.858 us; speedup vs baseline: 1.1872x; 1.1872x over previous
//
#include <hip/hip_runtime.h>
#include <math.h>

#define Bq 4
#define Hh 16
#define Lq 1024
#define Dd 64
#define Kk 8
#define QT 64         // q rows per block (32 per wave pair; qw in {0,1})
#define KT 128        // k rows per iteration; sw splits into 2x64
#define SRk 72        // K LDS row stride (bf16 elems) — 144 B = 9*16, b128-safe
#define SRv 136       // V^T LDS row stride (272 B = 17*16, b128-safe)
#define TB2 1088      // bias table entries, ONE copy (QT=64 window)
#define FMAX 8.0f     // fixed softmax shift (verified safe R1-R12)
#define LOG2E 1.44269504f

#define KSZ (KT * SRk * 2)           // 18432 B
#define VSZ (Dd * SRv * 2)           // 17408 B
#define BOFF (KSZ + VSZ)             // 35840 B
#define SMEM_BYTES (BOFF + TB2 * 4)  // 40192 B <= 40960 -> 4 blocks/CU

typedef __attribute__((ext_vector_type(8))) short short8;         // 8 bf16
typedef __attribute__((ext_vector_type(4))) unsigned int u32x4;   // 4 dwords
typedef __attribute__((ext_vector_type(16))) float f32x16;

// packed f32x2 -> bf16x2, round-half-up — BIT-IDENTICAL to R5's f2bh
// ((u+0x8000)>>16) but 3 VALU ops/pair via v_perm_b32 byte select.
// R9 post-mortem: __float22bfloat162_rn + reinterpret_cast took a local's
// address -> un-promoted alloca -> ~110 MB scratch traffic. Pure int ops only.
__device__ __forceinline__ unsigned int pk2(float a, float b) {
    return __builtin_amdgcn_perm(__float_as_uint(b) + 0x8000u,
                                 __float_as_uint(a) + 0x8000u,
                                 0x07060302u);
}

// j-permutation (verified R4-R12): V row j -> column slot so the S^T C/D
// register layout IS the PV A-fragment layout (P never touches LDS).
__device__ __forceinline__ int jperm(int j) {
    return (j & 32) | ((j & 8) << 1) | ((j & 4) << 1) | ((j & 16) >> 2) | (j & 3);
}

// ---------------------------------------------------------------------------
// Pre-pass (verified R12, bit-identical data): K/V f32 -> bf16 workspace.
//   Kb[bh][j][d] = bf16(K);  Vt[bh][d][s] = bf16(V^T), s=(j&~63)|jperm(j&63)
// ---------------------------------------------------------------------------
__global__ __launch_bounds__(256) void conv_kernel(
    const float* __restrict__ kp, const float* __restrict__ vp,
    unsigned short* __restrict__ kb, unsigned short* __restrict__ vt)
{
    const int tid = blockIdx.x * 256 + threadIdx.x;
    #pragma unroll
    for (int it = 0; it < 2; ++it) {
        const int n = (it * 262144 + tid) * 8;      // < 4,194,304
        float4 x0 = *(const float4*)(kp + n);
        float4 x1 = *(const float4*)(kp + n + 4);
        u32x4 a;
        a[0] = pk2(x0.x, x0.y); a[1] = pk2(x0.z, x0.w);
        a[2] = pk2(x1.x, x1.y); a[3] = pk2(x1.z, x1.w);
        *(u32x4*)(kb + n) = a;
    }
    const int bh = tid >> 12;
    const int dt = (tid >> 8) & 15;
    const int jt = tid & 255;
    const int j0 = 4 * jt;
    const float* vsrc = vp + ((size_t)bh * Lq + j0) * Dd + 4 * dt;
    float4 r0 = *(const float4*)(vsrc);
    float4 r1 = *(const float4*)(vsrc + Dd);
    float4 r2 = *(const float4*)(vsrc + 2 * Dd);
    float4 r3 = *(const float4*)(vsrc + 3 * Dd);
    const int slot = (j0 & ~63) | jperm(j0 & 63);
    unsigned short* vd = vt + ((size_t)bh * Dd + 4 * dt) * Lq + slot;
    uint2 w;
    w.x = pk2(r0.x, r1.x); w.y = pk2(r2.x, r3.x); *(uint2*)(vd)          = w;
    w.x = pk2(r0.y, r1.y); w.y = pk2(r2.y, r3.y); *(uint2*)(vd + Lq)     = w;
    w.x = pk2(r0.z, r1.z); w.y = pk2(r2.z, r3.z); *(uint2*)(vd + 2 * Lq) = w;
    w.x = pk2(r0.w, r1.w); w.y = pk2(r2.w, r3.w); *(uint2*)(vd + 3 * Lq) = w;
}

// ---------------------------------------------------------------------------
// R13: 4 INDEPENDENT barrier groups per CU.  Block = 256 (4 waves, QT=64),
// grid (64 bh, 16 q-tiles) = 1024 blocks = exactly 4/CU (LDS 40192 B).
// Same 16 waves/CU as R11 but each SIMD hosts 4 waves from 4 DIFFERENT
// blocks at different phases -> pipe phases overlap instead of summing
// (R11 post-mortem: VALU34+LDS~28+MFMA11+VMEM~10 ~= 100% of wall = pipes
// summing under block-wide phase-lock; R12 proved decorrelation alone is
// not sufficient when the LDS frag path is removed — so keep LDS frags).
// Staging is now a pure bf16 copy from the pre-pass workspace (no pk2
// VALU, half the staged HBM bytes); bias = ONE table copy, scalar b32
// reads (compiler fuses to ds_read2_b32), fed as MFMA C-init (R11-12).
// Wave w: qw=w>>1 (q rows qs+32qw..+31), sw=w&1 (k rows 64sw..+63 of tile).
// mfma_f32_32x32x16_bf16.  S^T = K Q^T, C/D: col=lane&31 (=i q-row),
// row=(r&3)+8*(r>>2)+4*(lane>>5) (=j_loc).  O = P V via jperm trick.
// Fixed-max softmax: p = exp2(S + (bias-FMAX)*log2e), Q pre-scaled 0.125*log2e.
// __launch_bounds__(256,2): 256-VGPR regalloc cap; NEVER arg=4 (R6/R7:
// (256,4) capped VGPRs at 64 -> ~700 MB scratch spills).
// ---------------------------------------------------------------------------
__global__ __launch_bounds__(256, 2) void attn_kernel(
    const float* __restrict__ qp,
    const float* __restrict__ off, const float* __restrict__ amp,
    const float* __restrict__ sh, const float* __restrict__ bpar,
    const unsigned short* __restrict__ kb,
    const unsigned short* __restrict__ vt,
    float* __restrict__ out)
{
    __shared__ __align__(16) char smem[SMEM_BYTES];
    short* k_s  = (short*)smem;              // [128][SRk] K rows [j][d]
    short* v_s  = (short*)(smem + KSZ);      // [64][SRv]  V^T [d][slot^swz]
    float* bias = (float*)(smem + BOFF);     // one copy, TB2 entries

    const int bh = blockIdx.x;            // fastest -> XCD = bh%8
    const int qs = blockIdx.y * QT;
    const int t  = threadIdx.x;
    const int w  = t >> 6;                // 0..3
    const int qw = w >> 1;                // q sub-block 0/1
    const int sw = w & 1;                 // k sub-tile 0/1
    const int lane = t & 63;
    const int l31 = lane & 31;
    const int h5  = lane >> 5;
    const int h   = bh & 15;

    // ---- bias table: (log(ksum+eps+bp) - |rel|*slope - FMAX)*log2e ----
    // index i -> rel = i - 63 - qs;  valid reads span i in [0, 1086].
    float slope = (h < Hh - 2) ? 4.605170185988092f * exp2f(-6.0f * (float)h / 13.0f) : 0.0f;
    #pragma unroll
    for (int it = 0; it < 5; ++it) {
        int i = it * 256 + t;
        if (i < TB2 - 1) {
            float rel = (float)(i - 63 - qs);
            float ksum = 0.0f;
            #pragma unroll
            for (int kk = 0; kk < Kk; ++kk) {
                float a = amp[kk * Hh + h];
                float o = off[kk * Hh + h];
                float s = sh[kk * Hh + h];
                float sgn = (a > 0.0f) ? 1.0f : ((a < 0.0f) ? -1.0f : 0.0f);
                ksum += fabsf(a) / (1.0f + __expf(-sgn * (rel - o) / s));
            }
            bias[i] = (logf(ksum + 1e-8f + bpar[h]) - fabsf(rel) * slope - FMAX) * LOG2E;
        }
    }

    // ---- Q B-frags (global, once), scale folded, packed converts ----
    const float QS = 0.125f * LOG2E;
    short8 bq[4];
    const float* qrow = qp + ((size_t)bh * Lq + qs + 32 * qw + l31) * Dd;
    #pragma unroll
    for (int c = 0; c < 4; ++c) {
        float4 x0 = *(const float4*)(qrow + c * 16 + h5 * 8);
        float4 x1 = *(const float4*)(qrow + c * 16 + h5 * 8 + 4);
        u32x4 a;
        a[0] = pk2(x0.x * QS, x0.y * QS);
        a[1] = pk2(x0.z * QS, x0.w * QS);
        a[2] = pk2(x1.x * QS, x1.y * QS);
        a[3] = pk2(x1.z * QS, x1.w * QS);
        bq[c] = __builtin_bit_cast(short8, a);
    }

    // ---- staging geometry: pure bf16 copy, 256 threads cover the tile.
    // K: thread = (row jr 0..127, half hh): 64 B contiguous -> wave reads
    //    32 full rows = 4 KB contiguous.  LDS addr jr*144+hh*64+c*16: 16B ok.
    // V: thread = (d-row dv 0..63, quarter qq): 64 B contiguous per thread
    //    (4-lane groups cover 256 B runs at 2 KB stride).  XOR swizzle is at
    //    8-short granularity -> each 16 B chunk maps to one 16 B LDS chunk.
    const int jr = t >> 1, hh = t & 1;
    const int dv = t >> 2, qq = t & 3;
    const int swzv = 8 * ((dv >> 3) & 7);
    const unsigned short* kbb = kb + (size_t)bh * Lq * Dd;
    const unsigned short* vtb = vt + ((size_t)bh * Dd + dv) * Lq;

    // ---- prefetch tile 0 ----
    u32x4 krg[4], vrg[4];
    #pragma unroll
    for (int c = 0; c < 4; ++c) {
        krg[c] = *(const u32x4*)(kbb + (size_t)jr * Dd + hh * 32 + c * 8);
        vrg[c] = *(const u32x4*)(vtb + qq * 32 + c * 8);
    }

    __syncthreads();                      // bias table visible

    // ---- write tile 0 ----
    #pragma unroll
    for (int c = 0; c < 4; ++c) {
        *(u32x4*)&k_s[jr * SRk + hh * 32 + c * 8] = krg[c];
        *(u32x4*)&v_s[dv * SRv + ((qq * 32 + c * 8) ^ swzv)] = vrg[c];
    }
    __syncthreads();

    // ---- accumulators ----
    f32x16 O0, O1;
    #pragma unroll
    for (int r = 0; r < 16; ++r) { O0[r] = 0.f; O1[r] = 0.f; }
    float l_part = 0.0f;

    const int L0 = 4 * h5 - 32 * qw - l31 + 63;   // bias lane offset (QT=64)

    #pragma unroll 1
    for (int kt = 0; kt < Lq / KT; ++kt) {        // 8 iterations
        const int ks = kt * KT;

        // prefetch next tile (VMEM overlaps compute below)
        if (kt < 7) {
            #pragma unroll
            for (int c = 0; c < 4; ++c) {
                krg[c] = *(const u32x4*)(kbb + (size_t)(ks + KT + jr) * Dd + hh * 32 + c * 8);
                vrg[c] = *(const u32x4*)(vtb + ks + KT + qq * 32 + c * 8);
            }
        }

        // ---- S init = bias (MFMA C-in); scalar b32 reads fuse to ds_read2
        f32x16 S0, S1;
        #pragma unroll
        for (int p = 0; p < 4; ++p) {
            int base0 = ks + 64 * sw + 8 * p + L0;
            #pragma unroll
            for (int q = 0; q < 4; ++q) {
                S0[4 * p + q] = bias[base0 + q];
                S1[4 * p + q] = bias[base0 + 32 + q];
            }
        }

        // ---- S^T = K Q^T + bias (this wave's sub-tile sw) ----
        #pragma unroll
        for (int c = 0; c < 4; ++c) {
            short8 ak0 = *(const short8*)&k_s[(64 * sw + l31) * SRk + c * 16 + h5 * 8];
            S0 = __builtin_amdgcn_mfma_f32_32x32x16_bf16(ak0, bq[c], S0, 0, 0, 0);
        }
        #pragma unroll
        for (int c = 0; c < 4; ++c) {
            short8 ak1 = *(const short8*)&k_s[(64 * sw + 32 + l31) * SRk + c * 16 + h5 * 8];
            S1 = __builtin_amdgcn_mfma_f32_32x32x16_bf16(ak1, bq[c], S1, 0, 0, 0);
        }

        // ---- softmax: p = exp2(S) (bias already inside) ----
        float lsum = 0.0f;
        #pragma unroll
        for (int r = 0; r < 16; ++r) {
            float e0 = __builtin_amdgcn_exp2f(S0[r]);
            float e1 = __builtin_amdgcn_exp2f(S1[r]);
            S0[r] = e0; S1[r] = e1;
            lsum += e0 + e1;
        }
        l_part += lsum;

        // ---- P A-frags in-register (jperm trick), packed converts ----
        short8 ap[4];
        #pragma unroll
        for (int c = 0; c < 4; ++c) {
            int b = (c & 1) * 4;
            u32x4 a;
            if (c >> 1) {
                a[0] = pk2(S1[b + 0], S1[b + 1]);
                a[1] = pk2(S1[b + 2], S1[b + 3]);
                a[2] = pk2(S1[b + 8], S1[b + 9]);
                a[3] = pk2(S1[b + 10], S1[b + 11]);
            } else {
                a[0] = pk2(S0[b + 0], S0[b + 1]);
                a[1] = pk2(S0[b + 2], S0[b + 3]);
                a[2] = pk2(S0[b + 8], S0[b + 9]);
                a[3] = pk2(S0[b + 10], S0[b + 11]);
            }
            ap[c] = __builtin_bit_cast(short8, a);
        }

        // ---- O += P V (sub-tile sw) ----
        #pragma unroll
        for (int nb = 0; nb < 2; ++nb) {
            int d = nb * 32 + l31;
            int swz = 8 * ((d >> 3) & 7);
            f32x16 acc = nb ? O1 : O0;
            #pragma unroll
            for (int c = 0; c < 4; ++c) {
                short8 bv = *(const short8*)&v_s[d * SRv + 64 * sw + ((c * 16 + h5 * 8) ^ swz)];
                acc = __builtin_amdgcn_mfma_f32_32x32x16_bf16(ap[c], bv, acc, 0, 0, 0);
            }
            if (nb) O1 = acc; else O0 = acc;
        }

        __syncthreads();                  // all 4 waves done reading tile
        if (kt < 7) {
            #pragma unroll
            for (int c = 0; c < 4; ++c) {
                *(u32x4*)&k_s[jr * SRk + hh * 32 + c * 8] = krg[c];
                *(u32x4*)&v_s[dv * SRv + ((qq * 32 + c * 8) ^ swzv)] = vrg[c];
            }
        }
        __syncthreads();                  // next tile visible
    }

    // ---- epilogue: wave pair (qw,0)+(qw,1) combine, normalize, store ----
    // k_s region dead (final barriers above); scratch 4x64x17 floats =
    // 17408 B fits in KSZ.  Stride 17 dwords -> 2-way bank alias only.
    l_part += __shfl_xor(l_part, 32);     // combine j-halves within wave
    float* red = (float*)smem;
    const int rb = (w * 64 + lane) * 17;
    #pragma unroll
    for (int r = 0; r < 16; ++r) red[rb + r] = sw ? O0[r] : O1[r];
    red[rb + 16] = l_part;
    __syncthreads();
    const int pb = ((w ^ 1) * 64 + lane) * 17;
    float inv = 1.0f / (l_part + red[pb + 16]);
    float* ob = out + ((size_t)bh * Lq + qs + 32 * qw) * Dd;
    #pragma unroll
    for (int r = 0; r < 16; ++r) {
        float o = (sw ? O1[r] : O0[r]) + red[pb + r];
        int rowp = (r & 3) + 8 * (r >> 2) + 4 * h5;
        float invp = __shfl(inv, rowp, 32);   // l lives at lane l31==row
        ob[(size_t)rowp * Dd + 32 * sw + l31] = o * invp;  // sw picks col half
    }
}

extern "C" void kernel_launch(void* const* d_in, const int* in_sizes, int n_in,
                              void* d_out, int out_size, void* d_ws, size_t ws_size,
                              hipStream_t stream) {
    const float* q   = (const float*)d_in[0];
    const float* k   = (const float*)d_in[1];
    const float* v   = (const float*)d_in[2];
    const float* off = (const float*)d_in[3];
    const float* amp = (const float*)d_in[4];
    const float* sh  = (const float*)d_in[5];
    const float* bp  = (const float*)d_in[6];
    float* out = (float*)d_out;

    // workspace: Kb (8 MiB) | Vt (8 MiB)
    unsigned short* kb = (unsigned short*)d_ws;
    unsigned short* vt = kb + (size_t)Bq * Hh * Lq * Dd;

    conv_kernel<<<dim3(1024), 256, 0, stream>>>(k, v, kb, vt);

    dim3 grid(Bq * Hh, Lq / QT);          // (64, 16), bh fastest -> XCD locality
    attn_kernel<<<grid, 256, 0, stream>>>(q, off, amp, sh, bp, kb, vt, out);
}